// Round 1
// baseline (143.740 us; speedup 1.0000x reference)
//
#include <hip/hip_runtime.h>
#include <math.h>

// Problem constants
#define H 32
#define W 32
#define OH 94
#define OW 94
#define NMESH (OH * OW)   // 8836
#define B 4
#define M 4096
#define BM (B * M)        // 16384

// Mesh chunking for the distance kernel: 8 chunks of ceil(8836/8)=1105,
// padded to 1108 (divisible by 4) with sentinel entries.
#define NCHUNK 8
#define CH 1105
#define CHPAD 1108
#define BPB (NCHUNK * CHPAD)   // per-batch padded mesh entries = 8864
#define MESH_TOTAL (B * BPB)   // 35456

__device__ __forceinline__ unsigned f2u_sortable(float f) {
    unsigned i = __float_as_uint(f);
    return (i & 0x80000000u) ? ~i : (i | 0x80000000u);
}
__device__ __forceinline__ float u2f_sortable(unsigned u) {
    return __uint_as_float((u & 0x80000000u) ? (u ^ 0x80000000u) : ~u);
}

// Kernel 1: bilinear mesh refine -> float4(x,y,z,||m||^2), init min array, zero out.
__global__ __launch_bounds__(256) void mesh_init_kernel(
        const float* __restrict__ nm, float4* __restrict__ mesh4,
        unsigned* __restrict__ minarr, float* __restrict__ out) {
    int e = blockIdx.x * 256 + threadIdx.x;
    if (e == 0) out[0] = 0.0f;
    if (e < BM) minarr[e] = 0xFFFFFFFFu;
    if (e >= MESH_TOTAL) return;

    int b = e / BPB;
    int r = e - b * BPB;
    int chunk = r / CHPAD;
    int k = r - chunk * CHPAD;
    int n = chunk * CH + k;
    if (k >= CH || n >= NMESH) {  // padding sentinel: never the min
        mesh4[e] = make_float4(0.f, 0.f, 0.f, 3.0e38f);
        return;
    }
    int oy = n / OW;
    int ox = n - oy * OW;
    float ys = (float)oy / 3.0f;
    float xs = (float)ox / 3.0f;
    int y0 = (int)floorf(ys); if (y0 > H - 2) y0 = H - 2;
    int x0 = (int)floorf(xs); if (x0 > W - 2) x0 = W - 2;
    float wy = ys - (float)y0;
    float wx = xs - (float)x0;

    const float* base = nm + b * 3 * H * W;
    float vals[3];
#pragma unroll
    for (int c = 0; c < 3; ++c) {
        const float* p = base + c * H * W + y0 * W + x0;
        float v00 = p[0], v01 = p[1], v10 = p[W], v11 = p[W + 1];
        float top = v00 * (1.0f - wx) + v01 * wx;
        float bot = v10 * (1.0f - wx) + v11 * wx;
        vals[c] = top * (1.0f - wy) + bot * wy;
    }
    float nrm = vals[0] * vals[0] + vals[1] * vals[1] + vals[2] * vals[2];
    mesh4[e] = make_float4(vals[0], vals[1], vals[2], nrm);
}

// Kernel 2: per pc point, min over one mesh chunk of (||m||^2 - 2 p.m); atomicMin.
// Mesh reads are wave-uniform -> expect scalar (s_load) path.
__global__ __launch_bounds__(256) void dist_kernel(
        const float* __restrict__ pc, const float4* __restrict__ mesh4,
        unsigned* __restrict__ minarr) {
    int b = blockIdx.z;                        // 4
    int i = blockIdx.y * 256 + threadIdx.x;    // pc point in [0, 4096)
    const float4* mp = mesh4 + b * BPB + blockIdx.x * CHPAD;

    float px = pc[(b * 3 + 0) * M + i];
    float py = pc[(b * 3 + 1) * M + i];
    float pz = pc[(b * 3 + 2) * M + i];

    float m0 = 3.0e38f, m1 = 3.0e38f, m2 = 3.0e38f, m3 = 3.0e38f;
    for (int j = 0; j < CHPAD; j += 4) {
        float4 a0 = mp[j + 0];
        float4 a1 = mp[j + 1];
        float4 a2 = mp[j + 2];
        float4 a3 = mp[j + 3];
        float s0 = fmaf(pz, a0.z, fmaf(py, a0.y, px * a0.x));
        float s1 = fmaf(pz, a1.z, fmaf(py, a1.y, px * a1.x));
        float s2 = fmaf(pz, a2.z, fmaf(py, a2.y, px * a2.x));
        float s3 = fmaf(pz, a3.z, fmaf(py, a3.y, px * a3.x));
        float c0 = fmaf(-2.0f, s0, a0.w);
        float c1 = fmaf(-2.0f, s1, a1.w);
        float c2 = fmaf(-2.0f, s2, a2.w);
        float c3 = fmaf(-2.0f, s3, a3.w);
        m0 = fminf(m0, c0);
        m1 = fminf(m1, c1);
        m2 = fminf(m2, c2);
        m3 = fminf(m3, c3);
    }
    float v = fminf(fminf(m0, m1), fminf(m2, m3));
    atomicMin(&minarr[b * M + i], f2u_sortable(v));
}

// Kernel 3: dist2_i = decoded_min_i + ||p_i||^2 ; mean via block reduce + atomicAdd.
__global__ __launch_bounds__(256) void reduce_kernel(
        const float* __restrict__ pc, const unsigned* __restrict__ minarr,
        float* __restrict__ out) {
    int e = blockIdx.x * 256 + threadIdx.x;  // [0, 16384)
    int b = e >> 12;
    int i = e & (M - 1);
    float px = pc[(b * 3 + 0) * M + i];
    float py = pc[(b * 3 + 1) * M + i];
    float pz = pc[(b * 3 + 2) * M + i];
    float pn = fmaf(px, px, fmaf(py, py, pz * pz));
    float d = u2f_sortable(minarr[e]) + pn;

    // wave64 reduce
    for (int off = 32; off > 0; off >>= 1)
        d += __shfl_down(d, off, 64);
    __shared__ float smem[4];
    int lane = threadIdx.x & 63;
    int wid = threadIdx.x >> 6;
    if (lane == 0) smem[wid] = d;
    __syncthreads();
    if (threadIdx.x == 0) {
        float s = (smem[0] + smem[1]) + (smem[2] + smem[3]);
        atomicAdd(out, s * (1.0f / (float)BM));
    }
}

extern "C" void kernel_launch(void* const* d_in, const int* in_sizes, int n_in,
                              void* d_out, int out_size, void* d_ws, size_t ws_size,
                              hipStream_t stream) {
    const float* nm = (const float*)d_in[0];   // (4,3,32,32)
    const float* pc = (const float*)d_in[1];   // (4,3,4096)
    float* out = (float*)d_out;                // scalar

    unsigned* minarr = (unsigned*)d_ws;                                  // 64 KiB
    float4* mesh4 = (float4*)((char*)d_ws + (size_t)BM * sizeof(unsigned)); // 16B-aligned

    int g1 = (MESH_TOTAL + 255) / 256;  // covers mesh entries, minarr init, out zero
    mesh_init_kernel<<<g1, 256, 0, stream>>>(nm, mesh4, minarr, out);

    dist_kernel<<<dim3(NCHUNK, M / 256, B), 256, 0, stream>>>(pc, mesh4, minarr);

    reduce_kernel<<<BM / 256, 256, 0, stream>>>(pc, minarr, out);
}

// Round 2
// 86.110 us; speedup vs baseline: 1.6693x; 1.6693x over previous
//
#include <hip/hip_runtime.h>
#include <math.h>

// Problem constants
#define H 32
#define W 32
#define OH 94
#define OW 94
#define NMESH (OH * OW)   // 8836
#define B 4
#define M 4096
#define BM (B * M)        // 16384

// Mesh chunking: 32 chunks of ceil(8836/32)=277, padded to 280 (div by 8).
#define NCHUNK 32
#define CH 277
#define CHPAD 280
#define BPB (NCHUNK * CHPAD)   // per-batch padded mesh entries = 8960
#define MESH_TOTAL (B * BPB)   // 35840

// Kernel 1: bilinear mesh refine -> float4(-2x, -2y, -2z, ||m||^2); zero out.
// Premultiplying by -2 (exact in fp32) turns the distance partial into a pure
// 3-FMA chain: d = fma(px, -2mx, fma(py, -2my, fma(pz, -2mz, ||m||^2))).
__global__ __launch_bounds__(256) void mesh_init_kernel(
        const float* __restrict__ nm, float4* __restrict__ mesh4,
        float* __restrict__ out) {
    int e = blockIdx.x * 256 + threadIdx.x;
    if (e == 0) out[0] = 0.0f;
    if (e >= MESH_TOTAL) return;

    int b = e / BPB;
    int r = e - b * BPB;
    int chunk = r / CHPAD;
    int k = r - chunk * CHPAD;
    int n = chunk * CH + k;
    if (k >= CH || n >= NMESH) {  // padding sentinel: never the min
        mesh4[e] = make_float4(0.f, 0.f, 0.f, 3.0e38f);
        return;
    }
    int oy = n / OW;
    int ox = n - oy * OW;
    float ys = (float)oy / 3.0f;
    float xs = (float)ox / 3.0f;
    int y0 = (int)floorf(ys); if (y0 > H - 2) y0 = H - 2;
    int x0 = (int)floorf(xs); if (x0 > W - 2) x0 = W - 2;
    float wy = ys - (float)y0;
    float wx = xs - (float)x0;

    const float* base = nm + b * 3 * H * W;
    float vals[3];
#pragma unroll
    for (int c = 0; c < 3; ++c) {
        const float* p = base + c * H * W + y0 * W + x0;
        float v00 = p[0], v01 = p[1], v10 = p[W], v11 = p[W + 1];
        float top = v00 * (1.0f - wx) + v01 * wx;
        float bot = v10 * (1.0f - wx) + v11 * wx;
        vals[c] = top * (1.0f - wy) + bot * wy;
    }
    float nrm = vals[0] * vals[0] + vals[1] * vals[1] + vals[2] * vals[2];
    mesh4[e] = make_float4(-2.0f * vals[0], -2.0f * vals[1], -2.0f * vals[2], nrm);
}

// Kernel 2: per pc point, min over one mesh chunk of (||m||^2 - 2 p.m).
// Mesh reads are wave-uniform -> scalar s_load path (VGPR_Count=8 confirmed R1).
// Partial mins go to minpart[chunk][b][i] (coalesced store, no atomics).
__global__ __launch_bounds__(256) void dist_kernel(
        const float* __restrict__ pc, const float4* __restrict__ mesh4,
        float* __restrict__ minpart) {
    int b = blockIdx.z;                        // 4
    int i = blockIdx.y * 256 + threadIdx.x;    // pc point in [0, 4096)
    int chunk = blockIdx.x;                    // 32
    const float4* mp = mesh4 + b * BPB + chunk * CHPAD;

    float px = pc[(b * 3 + 0) * M + i];
    float py = pc[(b * 3 + 1) * M + i];
    float pz = pc[(b * 3 + 2) * M + i];

    float m[8];
#pragma unroll
    for (int u = 0; u < 8; ++u) m[u] = 3.0e38f;

    for (int j = 0; j < CHPAD; j += 8) {
#pragma unroll
        for (int u = 0; u < 8; ++u) {
            float4 a = mp[j + u];
            float s = fmaf(px, a.x, fmaf(py, a.y, fmaf(pz, a.z, a.w)));
            m[u] = fminf(m[u], s);
        }
    }
    float v = fminf(fminf(fminf(m[0], m[1]), fminf(m[2], m[3])),
                    fminf(fminf(m[4], m[5]), fminf(m[6], m[7])));
    minpart[(chunk * B + b) * M + i] = v;
}

// Kernel 3: fold 32 chunk-partials, add ||p||^2, mean via block reduce + atomicAdd.
__global__ __launch_bounds__(256) void reduce_kernel(
        const float* __restrict__ pc, const float* __restrict__ minpart,
        float* __restrict__ out) {
    int e = blockIdx.x * 256 + threadIdx.x;  // [0, 16384)
    int b = e >> 12;
    int i = e & (M - 1);

    float v = 3.0e38f;
#pragma unroll 8
    for (int c = 0; c < NCHUNK; ++c)
        v = fminf(v, minpart[(c * B + b) * M + i]);

    float px = pc[(b * 3 + 0) * M + i];
    float py = pc[(b * 3 + 1) * M + i];
    float pz = pc[(b * 3 + 2) * M + i];
    float pn = fmaf(px, px, fmaf(py, py, pz * pz));
    float d = v + pn;

    // wave64 reduce
    for (int off = 32; off > 0; off >>= 1)
        d += __shfl_down(d, off, 64);
    __shared__ float smem[4];
    int lane = threadIdx.x & 63;
    int wid = threadIdx.x >> 6;
    if (lane == 0) smem[wid] = d;
    __syncthreads();
    if (threadIdx.x == 0) {
        float s = (smem[0] + smem[1]) + (smem[2] + smem[3]);
        atomicAdd(out, s * (1.0f / (float)BM));
    }
}

extern "C" void kernel_launch(void* const* d_in, const int* in_sizes, int n_in,
                              void* d_out, int out_size, void* d_ws, size_t ws_size,
                              hipStream_t stream) {
    const float* nm = (const float*)d_in[0];   // (4,3,32,32)
    const float* pc = (const float*)d_in[1];   // (4,3,4096)
    float* out = (float*)d_out;                // scalar

    float* minpart = (float*)d_ws;                                        // 2 MiB
    float4* mesh4 = (float4*)((char*)d_ws + (size_t)NCHUNK * BM * sizeof(float));

    int g1 = (MESH_TOTAL + 255) / 256;
    mesh_init_kernel<<<g1, 256, 0, stream>>>(nm, mesh4, out);

    dist_kernel<<<dim3(NCHUNK, M / 256, B), 256, 0, stream>>>(pc, mesh4, minpart);

    reduce_kernel<<<BM / 256, 256, 0, stream>>>(pc, minpart, out);
}